// Round 6
// baseline (235.608 us; speedup 1.0000x reference)
//
#include <hip/hip_runtime.h>
#include <math.h>

#define B_ 2
#define N_ 2048
#define D_ 1024
#define H_ 16
#define DH_ 64
#define ROWS (B_*N_)      // 4096
#define FOURD (4*D_)      // 4096
#define EPS_ 1e-5f

typedef short bf16x8 __attribute__((ext_vector_type(8)));
typedef unsigned short u16x8 __attribute__((ext_vector_type(8)));
typedef float f32x4  __attribute__((ext_vector_type(4)));
typedef float f32x16 __attribute__((ext_vector_type(16)));

typedef const __attribute__((address_space(1))) unsigned int* gp_t;
typedef __attribute__((address_space(3))) unsigned int* lp_t;

__device__ __forceinline__ unsigned short f2bf(float f) {
    unsigned int x = __float_as_uint(f);
    unsigned int r = (x + 0x7fffu + ((x >> 16) & 1u)) >> 16;   // RNE
    return (unsigned short)r;
}
__device__ __forceinline__ float bf2f(unsigned short u) {
    return __uint_as_float((unsigned int)u << 16);
}

// ---------------------------------------------------------------------------
// fused: fp32->bf16 casts of x (4M f4), Wqkvu (4M f4), Wout (1M f4) + lrpe
// cos/sin table gen (2048 x 1024, bf16): table[n][c] = cos/sin(theta[c]*n).
// ---------------------------------------------------------------------------
__global__ __launch_bounds__(256)
void cast_table(const float* __restrict__ x, const float* __restrict__ w1,
                const float* __restrict__ w2, const float* __restrict__ theta,
                unsigned short* __restrict__ xb, unsigned short* __restrict__ w1b,
                unsigned short* __restrict__ w2b, unsigned short* __restrict__ cos_t,
                unsigned short* __restrict__ sin_t)
{
    int i = blockIdx.x * 256 + threadIdx.x;
    if (i < 2359296) {
        const float* src; unsigned short* dst; int off;
        if (i < 1048576)      { src = x;  dst = xb;  off = i; }
        else if (i < 2097152) { src = w1; dst = w1b; off = i - 1048576; }
        else                  { src = w2; dst = w2b; off = i - 2097152; }
        float4 v = ((const float4*)src)[off];
        ushort4 o;
        o.x = f2bf(v.x); o.y = f2bf(v.y); o.z = f2bf(v.z); o.w = f2bf(v.w);
        ((ushort4*)dst)[off] = o;
    } else {
        int j  = i - 2359296;            // 0..524287
        int n  = j >> 8;                 // 0..2047
        int c0 = (j & 255) * 4;
        float4 tv = *(const float4*)&theta[c0];
        float t[4] = {tv.x, tv.y, tv.z, tv.w};
        ushort4 co, si;
        unsigned short* cp = (unsigned short*)&co;
        unsigned short* sp = (unsigned short*)&si;
#pragma unroll
        for (int k = 0; k < 4; ++k) {
            float s, c; __sincosf(t[k] * (float)n, &s, &c);
            cp[k] = f2bf(c); sp[k] = f2bf(s);
        }
        *(ushort4*)&cos_t[(size_t)n * D_ + c0] = co;
        *(ushort4*)&sin_t[(size_t)n * D_ + c0] = si;
    }
}

// ---------------------------------------------------------------------------
// bf16 MFMA GEMM, 128x128 tile, BK=64, XOR-swizzled LDS (0 bank conflicts),
// v_mfma_f32_32x32x16_bf16 (2x2 of 32x32 per wave). bf16 out, silu via __expf.
// ---------------------------------------------------------------------------
__global__ __launch_bounds__(256)
void gemm_bt_128(const unsigned short* __restrict__ A,
                 const unsigned short* __restrict__ Bw,
                 const float* __restrict__ bias, unsigned short* __restrict__ C,
                 int M, int N, int K, int siluLim)
{
    __shared__ unsigned short As[128 * 64];
    __shared__ unsigned short Bs[128 * 64];

    const int tid  = threadIdx.x;
    const int row0 = blockIdx.y * 128;
    const int col0 = blockIdx.x * 128;
    const int wave = tid >> 6;
    const int lane = tid & 63;
    const int wr   = (wave >> 1) * 64;
    const int wc   = (wave & 1) * 64;
    const int l31  = lane & 31;
    const int half = lane >> 5;
    const int xr   = lane & 7;           // row&7 for frag rows (row ≡ l31 mod 8)

    f32x16 acc[2][2] = {};

    // staging (unchanged from round 5): thread -> (row=tid>>3 (+32s), slot=tid&7),
    // global chunk = slot ^ (row&7)
    const int srow = tid >> 3;
    const int skk  = ((tid & 7) ^ (srow & 7)) * 8;
    const unsigned short* ag = A  + (size_t)(row0 + srow) * K + skk;
    const unsigned short* bg = Bw + (size_t)(col0 + srow) * K + skk;
    lp_t asd = (lp_t)(void*)&As[tid * 8];
    lp_t bsd = (lp_t)(void*)&Bs[tid * 8];

    for (int k0 = 0; k0 < K; k0 += 64) {
#pragma unroll
        for (int s = 0; s < 4; ++s) {
            __builtin_amdgcn_global_load_lds((gp_t)(const void*)(ag + (size_t)(32 * s) * K + k0), asd + s * 1024, 16, 0, 0);
            __builtin_amdgcn_global_load_lds((gp_t)(const void*)(bg + (size_t)(32 * s) * K + k0), bsd + s * 1024, 16, 0, 0);
        }
        __syncthreads();

#pragma unroll
        for (int ks = 0; ks < 4; ++ks) {
            const int slot = ((ks * 2 + half) ^ xr) * 8;
            bf16x8 a0 = *(const bf16x8*)&As[(wr +      l31) * 64 + slot];
            bf16x8 a1 = *(const bf16x8*)&As[(wr + 32 + l31) * 64 + slot];
            bf16x8 b0 = *(const bf16x8*)&Bs[(wc +      l31) * 64 + slot];
            bf16x8 b1 = *(const bf16x8*)&Bs[(wc + 32 + l31) * 64 + slot];
            acc[0][0] = __builtin_amdgcn_mfma_f32_32x32x16_bf16(a0, b0, acc[0][0], 0, 0, 0);
            acc[0][1] = __builtin_amdgcn_mfma_f32_32x32x16_bf16(a0, b1, acc[0][1], 0, 0, 0);
            acc[1][0] = __builtin_amdgcn_mfma_f32_32x32x16_bf16(a1, b0, acc[1][0], 0, 0, 0);
            acc[1][1] = __builtin_amdgcn_mfma_f32_32x32x16_bf16(a1, b1, acc[1][1], 0, 0, 0);
        }
        __syncthreads();
    }

    // C/D layout (32x32): col = lane&31, row = (reg&3) + 8*(reg>>2) + 4*(lane>>5)
#pragma unroll
    for (int i = 0; i < 2; ++i) {
#pragma unroll
        for (int j = 0; j < 2; ++j) {
            const int c  = col0 + wc + j * 32 + l31;
            const int rb = row0 + wr + i * 32 + 4 * half;
            const float bb = bias[c];
#pragma unroll
            for (int reg = 0; reg < 16; ++reg) {
                const int r = rb + (reg & 3) + 8 * (reg >> 2);
                float v = acc[i][j][reg] + bb;
                if (c < siluLim) v = v / (1.f + __expf(-v));   // silu
                C[(size_t)r * N + c] = f2bf(v);
            }
        }
    }
}

// ---------------------------------------------------------------------------
// bf16 MFMA GEMM, 128x64 tile, BK=64, same swizzle, 32x32x16 MFMA; fp32 out.
// Wave grid 2x2: wave tile 64 rows x 32 cols.
// ---------------------------------------------------------------------------
__global__ __launch_bounds__(256)
void gemm_bt_64(const unsigned short* __restrict__ A,
                const unsigned short* __restrict__ Bw,
                const float* __restrict__ bias, float* __restrict__ C,
                int M, int N, int K)
{
    __shared__ unsigned short As[128 * 64];
    __shared__ unsigned short Bs[64 * 64];

    const int tid  = threadIdx.x;
    const int row0 = blockIdx.y * 128;
    const int col0 = blockIdx.x * 64;
    const int wave = tid >> 6;
    const int lane = tid & 63;
    const int wr   = (wave >> 1) * 64;
    const int wc   = (wave & 1) * 32;
    const int l31  = lane & 31;
    const int half = lane >> 5;
    const int xr   = lane & 7;

    f32x16 acc[2] = {};

    const int srow = tid >> 3;
    const int skk  = ((tid & 7) ^ (srow & 7)) * 8;
    const unsigned short* ag = A  + (size_t)(row0 + srow) * K + skk;
    const unsigned short* bg = Bw + (size_t)(col0 + srow) * K + skk;
    lp_t asd = (lp_t)(void*)&As[tid * 8];
    lp_t bsd = (lp_t)(void*)&Bs[tid * 8];

    for (int k0 = 0; k0 < K; k0 += 64) {
#pragma unroll
        for (int s = 0; s < 4; ++s)
            __builtin_amdgcn_global_load_lds((gp_t)(const void*)(ag + (size_t)(32 * s) * K + k0), asd + s * 1024, 16, 0, 0);
#pragma unroll
        for (int s = 0; s < 2; ++s)
            __builtin_amdgcn_global_load_lds((gp_t)(const void*)(bg + (size_t)(32 * s) * K + k0), bsd + s * 1024, 16, 0, 0);
        __syncthreads();

#pragma unroll
        for (int ks = 0; ks < 4; ++ks) {
            const int slot = ((ks * 2 + half) ^ xr) * 8;
            bf16x8 a0 = *(const bf16x8*)&As[(wr +      l31) * 64 + slot];
            bf16x8 a1 = *(const bf16x8*)&As[(wr + 32 + l31) * 64 + slot];
            bf16x8 b0 = *(const bf16x8*)&Bs[(wc +      l31) * 64 + slot];
            acc[0] = __builtin_amdgcn_mfma_f32_32x32x16_bf16(a0, b0, acc[0], 0, 0, 0);
            acc[1] = __builtin_amdgcn_mfma_f32_32x32x16_bf16(a1, b0, acc[1], 0, 0, 0);
        }
        __syncthreads();
    }

    const int c = col0 + wc + l31;
    const float bb = bias[c];
#pragma unroll
    for (int i = 0; i < 2; ++i) {
        const int rb = row0 + wr + i * 32 + 4 * half;
#pragma unroll
        for (int reg = 0; reg < 16; ++reg) {
            const int r = rb + (reg & 3) + 8 * (reg >> 2);
            C[(size_t)r * N + c] = acc[i][reg] + bb;
        }
    }
}

// ---------------------------------------------------------------------------
// kv_mfma: one block per (b,h). 512 threads (8 waves). Loops 8 chunks of 256 n,
// staging lrpe(k) [d][n] and v [e][n] (bf16, table-based, ds_write_b64), MFMA
// accumulation in registers across chunks. No partials, no reduce, no atomics.
// Wave w owns d rows [16w, 16w+16).
// ---------------------------------------------------------------------------
__global__ __launch_bounds__(512)
void kv_mfma(const unsigned short* __restrict__ qkvu,
             const unsigned short* __restrict__ cos_t,
             const unsigned short* __restrict__ sin_t,
             float* __restrict__ kv)
{
    __shared__ unsigned short kl_s[128][264];  // [d][n], 256 + 8 pad
    __shared__ unsigned short v_s [64][264];   // [e][n]

    const int bh   = blockIdx.x;
    const int h    = bh & 15;
    const int b    = bh >> 4;
    const int tid  = threadIdx.x;
    const int lane = tid & 63;
    const int wave = tid >> 6;        // 0..7
    const int l15  = lane & 15;
    const int quad = lane >> 4;
    const int q4   = tid >> 3;        // nn quad 0..63
    const int g    = tid & 7;         // dh group 0..7
    const int nn0  = q4 * 4;

    f32x4 acc[4] = {};

    for (int chunk = 0; chunk < 8; ++chunk) {
        const int n0 = chunk * 256;
        // stage 4 consecutive n for 8 dh each; pack along n -> ds_write_b64
        ushort4 pc[8], ps[8], pv[8];
#pragma unroll
        for (int r = 0; r < 4; ++r) {
            const int n = n0 + nn0 + r;
            const unsigned short* qrow = qkvu + (size_t)(b * N_ + n) * FOURD;
            u16x8 k8 = *(const u16x8*)(qrow + D_     + h * DH_ + g * 8);
            u16x8 v8 = *(const u16x8*)(qrow + 2 * D_ + h * DH_ + g * 8);
            u16x8 c8 = *(const u16x8*)(cos_t + (size_t)n * D_ + h * DH_ + g * 8);
            u16x8 s8 = *(const u16x8*)(sin_t + (size_t)n * D_ + h * DH_ + g * 8);
#pragma unroll
            for (int j = 0; j < 8; ++j) {
                const float kf = bf2f(k8[j]);
                ((unsigned short*)&pc[j])[r] = f2bf(kf * bf2f(c8[j]));
                ((unsigned short*)&ps[j])[r] = f2bf(kf * bf2f(s8[j]));
                ((unsigned short*)&pv[j])[r] = v8[j];
            }
        }
#pragma unroll
        for (int j = 0; j < 8; ++j) {
            const int dh = g * 8 + j;
            *(ushort4*)&kl_s[dh][nn0]      = pc[j];
            *(ushort4*)&kl_s[64 + dh][nn0] = ps[j];
            *(ushort4*)&v_s[dh][nn0]       = pv[j];
        }
        __syncthreads();

#pragma unroll
        for (int ks = 0; ks < 8; ++ks) {          // 256 n in steps of 32
            bf16x8 a = *(const bf16x8*)&kl_s[wave * 16 + l15][ks * 32 + quad * 8];
#pragma unroll
            for (int j = 0; j < 4; ++j) {
                bf16x8 bfr = *(const bf16x8*)&v_s[j * 16 + l15][ks * 32 + quad * 8];
                acc[j] = __builtin_amdgcn_mfma_f32_16x16x32_bf16(a, bfr, acc[j], 0, 0, 0);
            }
        }
        __syncthreads();
    }

    float* kvp = kv + (size_t)bh * 8192;
    const int d0 = wave * 16 + quad * 4;
#pragma unroll
    for (int j = 0; j < 4; ++j) {
        const int e = j * 16 + l15;
#pragma unroll
        for (int r = 0; r < 4; ++r)
            kvp[(d0 + r) * 64 + e] = acc[j][r];
    }
}

// ---------------------------------------------------------------------------
// attn_ln: 8 rows per block. o = lrpe(q) @ KV (fp32), fused LayerNorm +
// u gating, bf16 output. Table-based lrpe (no sincos in hot path).
// ---------------------------------------------------------------------------
__global__ __launch_bounds__(256)
void attn_ln_kernel(const unsigned short* __restrict__ qkvu, const float* __restrict__ kvb,
                    const unsigned short* __restrict__ cos_t,
                    const unsigned short* __restrict__ sin_t,
                    const float* __restrict__ ln_w, const float* __restrict__ ln_b,
                    unsigned short* __restrict__ g)
{
    __shared__ float qc_s[8][1024];
    __shared__ float qs_s[8][1024];
    __shared__ float red[4][16];
    __shared__ float mured[8], rsred[8];

    const int row0 = blockIdx.x * 8;
    const int b    = row0 >> 11;
    const int tid  = threadIdx.x;
    const int lane = tid & 63;
    const int wave = tid >> 6;

    for (int i = tid; i < 2048; i += 256) {
        const int r  = i >> 8;
        const int ci = (i & 255) * 4;
        const int n  = (row0 + r) & (N_ - 1);
        ushort4 qv = *(const ushort4*)&qkvu[(size_t)(row0 + r) * FOURD + ci];
        ushort4 cv = *(const ushort4*)&cos_t[(size_t)n * D_ + ci];
        ushort4 sv = *(const ushort4*)&sin_t[(size_t)n * D_ + ci];
        float4 co, so;
        co.x = bf2f(qv.x) * bf2f(cv.x); so.x = bf2f(qv.x) * bf2f(sv.x);
        co.y = bf2f(qv.y) * bf2f(cv.y); so.y = bf2f(qv.y) * bf2f(sv.y);
        co.z = bf2f(qv.z) * bf2f(cv.z); so.z = bf2f(qv.z) * bf2f(sv.z);
        co.w = bf2f(qv.w) * bf2f(cv.w); so.w = bf2f(qv.w) * bf2f(sv.w);
        *(float4*)&qc_s[r][ci] = co;
        *(float4*)&qs_s[r][ci] = so;
    }
    __syncthreads();

    const int c0 = tid * 4;
    const int h  = c0 >> 6;
    const int e0 = c0 & 63;
    const float* kvp = kvb + (size_t)(b * H_ + h) * 8192;

    float o[8][4] = {};
    for (int d = 0; d < 64; ++d) {
        float4 kc = *(const float4*)&kvp[d * 64 + e0];
        float4 ks = *(const float4*)&kvp[(64 + d) * 64 + e0];
#pragma unroll
        for (int r = 0; r < 8; ++r) {
            const float qc = qc_s[r][h * 64 + d];
            const float qs = qs_s[r][h * 64 + d];
            o[r][0] = fmaf(qc, kc.x, fmaf(qs, ks.x, o[r][0]));
            o[r][1] = fmaf(qc, kc.y, fmaf(qs, ks.y, o[r][1]));
            o[r][2] = fmaf(qc, kc.z, fmaf(qs, ks.z, o[r][2]));
            o[r][3] = fmaf(qc, kc.w, fmaf(qs, ks.w, o[r][3]));
        }
    }

    float sum[8], sq[8];
#pragma unroll
    for (int r = 0; r < 8; ++r) {
        sum[r] = o[r][0] + o[r][1] + o[r][2] + o[r][3];
        sq[r]  = o[r][0]*o[r][0] + o[r][1]*o[r][1] + o[r][2]*o[r][2] + o[r][3]*o[r][3];
    }
#pragma unroll
    for (int off = 32; off; off >>= 1)
#pragma unroll
        for (int r = 0; r < 8; ++r) {
            sum[r] += __shfl_down(sum[r], off, 64);
            sq[r]  += __shfl_down(sq[r],  off, 64);
        }
    if (lane == 0)
#pragma unroll
        for (int r = 0; r < 8; ++r) { red[wave][r] = sum[r]; red[wave][8 + r] = sq[r]; }
    __syncthreads();
    if (tid < 8) {
        const float s  = red[0][tid] + red[1][tid] + red[2][tid] + red[3][tid];
        const float q2 = red[0][8+tid] + red[1][8+tid] + red[2][8+tid] + red[3][8+tid];
        const float mu = s * (1.f / (float)D_);
        const float var = q2 * (1.f / (float)D_) - mu * mu;
        mured[tid] = mu;
        rsred[tid] = rsqrtf(var + EPS_);
    }
    __syncthreads();

    float4 wv = *(const float4*)&ln_w[c0];
    float4 bv = *(const float4*)&ln_b[c0];
#pragma unroll
    for (int r = 0; r < 8; ++r) {
        ushort4 uvb = *(const ushort4*)&qkvu[(size_t)(row0 + r) * FOURD + 3 * D_ + c0];
        const float mu = mured[r], rs = rsred[r];
        ushort4 ov;
        ov.x = f2bf(((o[r][0] - mu) * rs * wv.x + bv.x) * bf2f(uvb.x));
        ov.y = f2bf(((o[r][1] - mu) * rs * wv.y + bv.y) * bf2f(uvb.y));
        ov.z = f2bf(((o[r][2] - mu) * rs * wv.z + bv.z) * bf2f(uvb.z));
        ov.w = f2bf(((o[r][3] - mu) * rs * wv.w + bv.w) * bf2f(uvb.w));
        *(ushort4*)&g[(size_t)(row0 + r) * D_ + c0] = ov;
    }
}

// ---------------------------------------------------------------------------
extern "C" void kernel_launch(void* const* d_in, const int* in_sizes, int n_in,
                              void* d_out, int out_size, void* d_ws, size_t ws_size,
                              hipStream_t stream)
{
    const float* x     = (const float*)d_in[0];
    const float* Wqkvu = (const float*)d_in[2];
    const float* bqkvu = (const float*)d_in[3];
    const float* Wout  = (const float*)d_in[4];
    const float* bout  = (const float*)d_in[5];
    const float* theta = (const float*)d_in[6];
    const float* ln_w  = (const float*)d_in[7];
    const float* ln_b  = (const float*)d_in[8];
    float* out = (float*)d_out;

    // workspace layout
    char* ws = (char*)d_ws;
    unsigned short* qkvu  = (unsigned short*)ws; ws += (size_t)ROWS * FOURD * 2;   // 32 MiB
    float*          kvbuf = (float*)ws;          ws += (size_t)B_ * H_ * 8192 * 4; // 1 MiB
    unsigned short* wqb   = (unsigned short*)ws; ws += (size_t)FOURD * D_ * 2;     // 8 MiB
    unsigned short* wob   = (unsigned short*)ws; ws += (size_t)D_ * D_ * 2;        // 2 MiB
    unsigned short* xb    = (unsigned short*)ws; ws += (size_t)ROWS * D_ * 2;      // 8 MiB
    unsigned short* cost  = (unsigned short*)ws; ws += (size_t)N_ * D_ * 2;        // 4 MiB
    unsigned short* sint  = (unsigned short*)ws; ws += (size_t)N_ * D_ * 2;        // 4 MiB
    unsigned short* gb    = (unsigned short*)ws;                                   // 8 MiB

    dim3 blk(256);
    // casts + lrpe table: 2359296 + 524288 = 2883584 threads
    cast_table<<<dim3(2883584 / 256), blk, 0, stream>>>(
        x, Wqkvu, Wout, theta, xb, wqb, wob, cost, sint);

    // qkvu = x @ Wqkvu^T + b (bf16 out), silu on q,k columns
    gemm_bt_128<<<dim3(FOURD / 128, ROWS / 128), blk, 0, stream>>>(
        xb, wqb, bqkvu, qkvu, ROWS, FOURD, D_, 2 * D_);
    // KV = lrpe(k)^T v per (b,h), single pass
    kv_mfma<<<dim3(B_ * H_), dim3(512), 0, stream>>>(qkvu, cost, sint, kvbuf);
    // o = lrpe(q) @ KV, fused LN + u gating -> g (bf16)
    attn_ln_kernel<<<dim3(ROWS / 8), blk, 0, stream>>>(
        qkvu, kvbuf, cost, sint, ln_w, ln_b, gb);
    // out = g @ Wout^T + bout
    gemm_bt_64<<<dim3(D_ / 64, ROWS / 128), blk, 0, stream>>>(
        gb, wob, bout, out, ROWS, D_, D_);
}

// Round 7
// 214.158 us; speedup vs baseline: 1.1002x; 1.1002x over previous
//
#include <hip/hip_runtime.h>
#include <math.h>

#define B_ 2
#define N_ 2048
#define D_ 1024
#define H_ 16
#define DH_ 64
#define ROWS (B_*N_)      // 4096
#define FOURD (4*D_)      // 4096
#define EPS_ 1e-5f

typedef short bf16x8 __attribute__((ext_vector_type(8)));
typedef unsigned short u16x8 __attribute__((ext_vector_type(8)));
typedef float f32x4  __attribute__((ext_vector_type(4)));

typedef const __attribute__((address_space(1))) unsigned int* gp_t;
typedef __attribute__((address_space(3))) unsigned int* lp_t;

__device__ __forceinline__ unsigned short f2bf(float f) {
    unsigned int x = __float_as_uint(f);
    unsigned int r = (x + 0x7fffu + ((x >> 16) & 1u)) >> 16;   // RNE
    return (unsigned short)r;
}
__device__ __forceinline__ float bf2f(unsigned short u) {
    return __uint_as_float((unsigned int)u << 16);
}

// ---------------------------------------------------------------------------
// fused: fp32->bf16 casts of x, Wqkvu, Wout + lrpe cos/sin bf16 tables
// table[n][c] = cos/sin(theta[c]*n), 2048 x 1024.
// ---------------------------------------------------------------------------
__global__ __launch_bounds__(256)
void cast_table(const float* __restrict__ x, const float* __restrict__ w1,
                const float* __restrict__ w2, const float* __restrict__ theta,
                unsigned short* __restrict__ xb, unsigned short* __restrict__ w1b,
                unsigned short* __restrict__ w2b, unsigned short* __restrict__ cos_t,
                unsigned short* __restrict__ sin_t)
{
    int i = blockIdx.x * 256 + threadIdx.x;
    if (i < 2359296) {
        const float* src; unsigned short* dst; int off;
        if (i < 1048576)      { src = x;  dst = xb;  off = i; }
        else if (i < 2097152) { src = w1; dst = w1b; off = i - 1048576; }
        else                  { src = w2; dst = w2b; off = i - 2097152; }
        float4 v = ((const float4*)src)[off];
        ushort4 o;
        o.x = f2bf(v.x); o.y = f2bf(v.y); o.z = f2bf(v.z); o.w = f2bf(v.w);
        ((ushort4*)dst)[off] = o;
    } else {
        int j  = i - 2359296;            // 0..524287
        int n  = j >> 8;                 // 0..2047
        int c0 = (j & 255) * 4;
        float4 tv = *(const float4*)&theta[c0];
        float t[4] = {tv.x, tv.y, tv.z, tv.w};
        ushort4 co, si;
        unsigned short* cp = (unsigned short*)&co;
        unsigned short* sp = (unsigned short*)&si;
#pragma unroll
        for (int k = 0; k < 4; ++k) {
            float s, c; __sincosf(t[k] * (float)n, &s, &c);
            cp[k] = f2bf(c); sp[k] = f2bf(s);
        }
        *(ushort4*)&cos_t[(size_t)n * D_ + c0] = co;
        *(ushort4*)&sin_t[(size_t)n * D_ + c0] = si;
    }
}

// ---------------------------------------------------------------------------
// bf16 MFMA GEMM, 128x128 tile, BK=64, XOR-swizzled LDS (0 bank conflicts,
// measured r5), 16x16x32 MFMA (4x4 per wave). bf16 out, silu via __expf.
// NOTE: do NOT switch to 32x32 MFMA — its 32-row fragment read pattern is
// structurally 4-way bank-conflicted with this lane-linear LDS layout (r6).
// ---------------------------------------------------------------------------
__global__ __launch_bounds__(256)
void gemm_bt_128(const unsigned short* __restrict__ A,
                 const unsigned short* __restrict__ Bw,
                 const float* __restrict__ bias, unsigned short* __restrict__ C,
                 int M, int N, int K, int siluLim)
{
    __shared__ unsigned short As[128 * 64];
    __shared__ unsigned short Bs[128 * 64];

    const int tid  = threadIdx.x;
    const int row0 = blockIdx.y * 128;
    const int col0 = blockIdx.x * 128;
    const int wave = tid >> 6;
    const int lane = tid & 63;
    const int wr   = (wave >> 1) * 64;
    const int wc   = (wave & 1) * 64;
    const int l15  = lane & 15;
    const int quad = lane >> 4;
    const int xr   = l15 & 7;            // read-side xor key (row&7 == l15&7)

    f32x4 acc[4][4] = {};

    // staging: thread -> (row = tid>>3 + 32s, slot = tid&7); global chunk = slot^(row&7)
    const int srow = tid >> 3;
    const int skk  = ((tid & 7) ^ (srow & 7)) * 8;
    const unsigned short* ag = A  + (size_t)(row0 + srow) * K + skk;
    const unsigned short* bg = Bw + (size_t)(col0 + srow) * K + skk;
    lp_t asd = (lp_t)(void*)&As[tid * 8];
    lp_t bsd = (lp_t)(void*)&Bs[tid * 8];

    for (int k0 = 0; k0 < K; k0 += 64) {
#pragma unroll
        for (int s = 0; s < 4; ++s) {
            __builtin_amdgcn_global_load_lds((gp_t)(const void*)(ag + (size_t)(32 * s) * K + k0), asd + s * 1024, 16, 0, 0);
            __builtin_amdgcn_global_load_lds((gp_t)(const void*)(bg + (size_t)(32 * s) * K + k0), bsd + s * 1024, 16, 0, 0);
        }
        __syncthreads();

#pragma unroll
        for (int ksub = 0; ksub < 2; ++ksub) {
            const int slot = ((ksub * 4 + quad) ^ xr) * 8;
            bf16x8 af[4], bfr[4];
#pragma unroll
            for (int i = 0; i < 4; ++i)
                af[i] = *(const bf16x8*)&As[(wr + i * 16 + l15) * 64 + slot];
#pragma unroll
            for (int j = 0; j < 4; ++j)
                bfr[j] = *(const bf16x8*)&Bs[(wc + j * 16 + l15) * 64 + slot];
#pragma unroll
            for (int i = 0; i < 4; ++i)
#pragma unroll
                for (int j = 0; j < 4; ++j)
                    acc[i][j] = __builtin_amdgcn_mfma_f32_16x16x32_bf16(af[i], bfr[j], acc[i][j], 0, 0, 0);
        }
        __syncthreads();
    }

#pragma unroll
    for (int i = 0; i < 4; ++i) {
        const int r0 = row0 + wr + i * 16 + quad * 4;
#pragma unroll
        for (int j = 0; j < 4; ++j) {
            const int c = col0 + wc + j * 16 + l15;
            const float bb = bias[c];
#pragma unroll
            for (int r = 0; r < 4; ++r) {
                float v = acc[i][j][r] + bb;
                if (c < siluLim) v = v / (1.f + __expf(-v));   // silu (HW exp)
                C[(size_t)(r0 + r) * N + c] = f2bf(v);
            }
        }
    }
}

// ---------------------------------------------------------------------------
// bf16 MFMA GEMM, 128x64 tile, BK=64, same swizzle, 16x16x32 MFMA; fp32 out.
// ---------------------------------------------------------------------------
__global__ __launch_bounds__(256)
void gemm_bt_64(const unsigned short* __restrict__ A,
                const unsigned short* __restrict__ Bw,
                const float* __restrict__ bias, float* __restrict__ C,
                int M, int N, int K)
{
    __shared__ unsigned short As[128 * 64];
    __shared__ unsigned short Bs[64 * 64];

    const int tid  = threadIdx.x;
    const int row0 = blockIdx.y * 128;
    const int col0 = blockIdx.x * 64;
    const int wave = tid >> 6;
    const int lane = tid & 63;
    const int wr   = wave * 32;
    const int l15  = lane & 15;
    const int quad = lane >> 4;
    const int xr   = l15 & 7;

    f32x4 acc[2][4] = {};

    const int srow = tid >> 3;
    const int skk  = ((tid & 7) ^ (srow & 7)) * 8;
    const unsigned short* ag = A  + (size_t)(row0 + srow) * K + skk;
    const unsigned short* bg = Bw + (size_t)(col0 + srow) * K + skk;
    lp_t asd = (lp_t)(void*)&As[tid * 8];
    lp_t bsd = (lp_t)(void*)&Bs[tid * 8];

    for (int k0 = 0; k0 < K; k0 += 64) {
#pragma unroll
        for (int s = 0; s < 4; ++s)
            __builtin_amdgcn_global_load_lds((gp_t)(const void*)(ag + (size_t)(32 * s) * K + k0), asd + s * 1024, 16, 0, 0);
#pragma unroll
        for (int s = 0; s < 2; ++s)
            __builtin_amdgcn_global_load_lds((gp_t)(const void*)(bg + (size_t)(32 * s) * K + k0), bsd + s * 1024, 16, 0, 0);
        __syncthreads();

#pragma unroll
        for (int ksub = 0; ksub < 2; ++ksub) {
            const int slot = ((ksub * 4 + quad) ^ xr) * 8;
            bf16x8 af[2], bfr[4];
#pragma unroll
            for (int i = 0; i < 2; ++i)
                af[i] = *(const bf16x8*)&As[(wr + i * 16 + l15) * 64 + slot];
#pragma unroll
            for (int j = 0; j < 4; ++j)
                bfr[j] = *(const bf16x8*)&Bs[(j * 16 + l15) * 64 + slot];
#pragma unroll
            for (int i = 0; i < 2; ++i)
#pragma unroll
                for (int j = 0; j < 4; ++j)
                    acc[i][j] = __builtin_amdgcn_mfma_f32_16x16x32_bf16(af[i], bfr[j], acc[i][j], 0, 0, 0);
        }
        __syncthreads();
    }

#pragma unroll
    for (int i = 0; i < 2; ++i) {
        const int r0 = row0 + wr + i * 16 + quad * 4;
#pragma unroll
        for (int j = 0; j < 4; ++j) {
            const int c = col0 + j * 16 + l15;
            const float bb = bias[c];
#pragma unroll
            for (int r = 0; r < 4; ++r)
                C[(size_t)(r0 + r) * N + c] = acc[i][j][r] + bb;
        }
    }
}

// ---------------------------------------------------------------------------
// kv_mfma: per (b,h, 128-n chunk): partial KV[128 d, 64 e] via MFMA.
// grid = 32 bh * 16 chunks = 512 blocks (parallelism!, r6's 32-block version
// was latency-bound). Table-based lrpe staging, ds_write_b64, fp32 partials.
// Wave w owns d rows [32w, 32w+32).
// ---------------------------------------------------------------------------
__global__ __launch_bounds__(256)
void kv_mfma(const unsigned short* __restrict__ qkvu,
             const unsigned short* __restrict__ cos_t,
             const unsigned short* __restrict__ sin_t,
             float* __restrict__ part)
{
    __shared__ unsigned short kl_s[128][136];  // [d][n], 128 + 8 pad
    __shared__ unsigned short v_s [64][136];   // [e][n]

    const int bid   = blockIdx.x;
    const int chunk = bid & 15;
    const int bh    = bid >> 4;
    const int h     = bh & 15;
    const int b     = bh >> 4;
    const int tid   = threadIdx.x;
    const int lane  = tid & 63;
    const int wave  = tid >> 6;
    const int l15   = lane & 15;
    const int quad  = lane >> 4;
    const int n0    = chunk * 128;

    // staging: thread -> (g = tid&7 dh-group, nn0 = (tid>>3)*4), 4 consecutive n
    {
        const int g   = tid & 7;
        const int nn0 = (tid >> 3) * 4;
        ushort4 pc[8], ps[8], pv[8];
#pragma unroll
        for (int r = 0; r < 4; ++r) {
            const int n = n0 + nn0 + r;
            const unsigned short* qrow = qkvu + (size_t)(b * N_ + n) * FOURD;
            u16x8 k8 = *(const u16x8*)(qrow + D_     + h * DH_ + g * 8);
            u16x8 v8 = *(const u16x8*)(qrow + 2 * D_ + h * DH_ + g * 8);
            u16x8 c8 = *(const u16x8*)(cos_t + (size_t)n * D_ + h * DH_ + g * 8);
            u16x8 s8 = *(const u16x8*)(sin_t + (size_t)n * D_ + h * DH_ + g * 8);
#pragma unroll
            for (int j = 0; j < 8; ++j) {
                const float kf = bf2f(k8[j]);
                ((unsigned short*)&pc[j])[r] = f2bf(kf * bf2f(c8[j]));
                ((unsigned short*)&ps[j])[r] = f2bf(kf * bf2f(s8[j]));
                ((unsigned short*)&pv[j])[r] = v8[j];
            }
        }
#pragma unroll
        for (int j = 0; j < 8; ++j) {
            const int dh = g * 8 + j;
            *(ushort4*)&kl_s[dh][nn0]      = pc[j];
            *(ushort4*)&kl_s[64 + dh][nn0] = ps[j];
            *(ushort4*)&v_s[dh][nn0]       = pv[j];
        }
    }
    __syncthreads();

    f32x4 acc[2][4] = {};
#pragma unroll
    for (int ks = 0; ks < 4; ++ks) {            // 128 n in steps of 32
        bf16x8 a0 = *(const bf16x8*)&kl_s[wave * 32 +      l15][ks * 32 + quad * 8];
        bf16x8 a1 = *(const bf16x8*)&kl_s[wave * 32 + 16 + l15][ks * 32 + quad * 8];
#pragma unroll
        for (int j = 0; j < 4; ++j) {
            bf16x8 bfr = *(const bf16x8*)&v_s[j * 16 + l15][ks * 32 + quad * 8];
            acc[0][j] = __builtin_amdgcn_mfma_f32_16x16x32_bf16(a0, bfr, acc[0][j], 0, 0, 0);
            acc[1][j] = __builtin_amdgcn_mfma_f32_16x16x32_bf16(a1, bfr, acc[1][j], 0, 0, 0);
        }
    }

    float* pp = part + ((size_t)bh * 16 + chunk) * 8192;
#pragma unroll
    for (int i = 0; i < 2; ++i) {
        const int d0 = wave * 32 + i * 16 + quad * 4;
#pragma unroll
        for (int j = 0; j < 4; ++j) {
            const int e = j * 16 + l15;
#pragma unroll
            for (int r = 0; r < 4; ++r)
                pp[(d0 + r) * 64 + e] = acc[i][j][r];
        }
    }
}

// ---------------------------------------------------------------------------
// kv_reduce: kv[bh][i] = sum over 16 chunk partials.
// ---------------------------------------------------------------------------
__global__ __launch_bounds__(256)
void kv_reduce(const float* __restrict__ part, float* __restrict__ kv)
{
    const int i  = blockIdx.x * 256 + threadIdx.x;
    const int bh = i >> 13;
    const float* pp = part + ((size_t)bh * 16) * 8192 + (i & 8191);
    float s = 0.f;
#pragma unroll
    for (int c = 0; c < 16; ++c) s += pp[c * 8192];
    kv[i] = s;
}

// ---------------------------------------------------------------------------
// attn_ln: 8 rows per block. o = lrpe(q) @ KV (fp32), fused LayerNorm +
// u gating, bf16 output. Table-based lrpe.
// ---------------------------------------------------------------------------
__global__ __launch_bounds__(256)
void attn_ln_kernel(const unsigned short* __restrict__ qkvu, const float* __restrict__ kvb,
                    const unsigned short* __restrict__ cos_t,
                    const unsigned short* __restrict__ sin_t,
                    const float* __restrict__ ln_w, const float* __restrict__ ln_b,
                    unsigned short* __restrict__ g)
{
    __shared__ float qc_s[8][1024];
    __shared__ float qs_s[8][1024];
    __shared__ float red[4][16];
    __shared__ float mured[8], rsred[8];

    const int row0 = blockIdx.x * 8;
    const int b    = row0 >> 11;
    const int tid  = threadIdx.x;
    const int lane = tid & 63;
    const int wave = tid >> 6;

    for (int i = tid; i < 2048; i += 256) {
        const int r  = i >> 8;
        const int ci = (i & 255) * 4;
        const int n  = (row0 + r) & (N_ - 1);
        ushort4 qv = *(const ushort4*)&qkvu[(size_t)(row0 + r) * FOURD + ci];
        ushort4 cv = *(const ushort4*)&cos_t[(size_t)n * D_ + ci];
        ushort4 sv = *(const ushort4*)&sin_t[(size_t)n * D_ + ci];
        float4 co, so;
        co.x = bf2f(qv.x) * bf2f(cv.x); so.x = bf2f(qv.x) * bf2f(sv.x);
        co.y = bf2f(qv.y) * bf2f(cv.y); so.y = bf2f(qv.y) * bf2f(sv.y);
        co.z = bf2f(qv.z) * bf2f(cv.z); so.z = bf2f(qv.z) * bf2f(sv.z);
        co.w = bf2f(qv.w) * bf2f(cv.w); so.w = bf2f(qv.w) * bf2f(sv.w);
        *(float4*)&qc_s[r][ci] = co;
        *(float4*)&qs_s[r][ci] = so;
    }
    __syncthreads();

    const int c0 = tid * 4;
    const int h  = c0 >> 6;
    const int e0 = c0 & 63;
    const float* kvp = kvb + (size_t)(b * H_ + h) * 8192;

    float o[8][4] = {};
    for (int d = 0; d < 64; ++d) {
        float4 kc = *(const float4*)&kvp[d * 64 + e0];
        float4 ks = *(const float4*)&kvp[(64 + d) * 64 + e0];
#pragma unroll
        for (int r = 0; r < 8; ++r) {
            const float qc = qc_s[r][h * 64 + d];
            const float qs = qs_s[r][h * 64 + d];
            o[r][0] = fmaf(qc, kc.x, fmaf(qs, ks.x, o[r][0]));
            o[r][1] = fmaf(qc, kc.y, fmaf(qs, ks.y, o[r][1]));
            o[r][2] = fmaf(qc, kc.z, fmaf(qs, ks.z, o[r][2]));
            o[r][3] = fmaf(qc, kc.w, fmaf(qs, ks.w, o[r][3]));
        }
    }

    float sum[8], sq[8];
#pragma unroll
    for (int r = 0; r < 8; ++r) {
        sum[r] = o[r][0] + o[r][1] + o[r][2] + o[r][3];
        sq[r]  = o[r][0]*o[r][0] + o[r][1]*o[r][1] + o[r][2]*o[r][2] + o[r][3]*o[r][3];
    }
#pragma unroll
    for (int off = 32; off; off >>= 1)
#pragma unroll
        for (int r = 0; r < 8; ++r) {
            sum[r] += __shfl_down(sum[r], off, 64);
            sq[r]  += __shfl_down(sq[r],  off, 64);
        }
    if (lane == 0)
#pragma unroll
        for (int r = 0; r < 8; ++r) { red[wave][r] = sum[r]; red[wave][8 + r] = sq[r]; }
    __syncthreads();
    if (tid < 8) {
        const float s  = red[0][tid] + red[1][tid] + red[2][tid] + red[3][tid];
        const float q2 = red[0][8+tid] + red[1][8+tid] + red[2][8+tid] + red[3][8+tid];
        const float mu = s * (1.f / (float)D_);
        const float var = q2 * (1.f / (float)D_) - mu * mu;
        mured[tid] = mu;
        rsred[tid] = rsqrtf(var + EPS_);
    }
    __syncthreads();

    float4 wv = *(const float4*)&ln_w[c0];
    float4 bv = *(const float4*)&ln_b[c0];
#pragma unroll
    for (int r = 0; r < 8; ++r) {
        ushort4 uvb = *(const ushort4*)&qkvu[(size_t)(row0 + r) * FOURD + 3 * D_ + c0];
        const float mu = mured[r], rs = rsred[r];
        ushort4 ov;
        ov.x = f2bf(((o[r][0] - mu) * rs * wv.x + bv.x) * bf2f(uvb.x));
        ov.y = f2bf(((o[r][1] - mu) * rs * wv.y + bv.y) * bf2f(uvb.y));
        ov.z = f2bf(((o[r][2] - mu) * rs * wv.z + bv.z) * bf2f(uvb.z));
        ov.w = f2bf(((o[r][3] - mu) * rs * wv.w + bv.w) * bf2f(uvb.w));
        *(ushort4*)&g[(size_t)(row0 + r) * D_ + c0] = ov;
    }
}

// ---------------------------------------------------------------------------
extern "C" void kernel_launch(void* const* d_in, const int* in_sizes, int n_in,
                              void* d_out, int out_size, void* d_ws, size_t ws_size,
                              hipStream_t stream)
{
    const float* x     = (const float*)d_in[0];
    const float* Wqkvu = (const float*)d_in[2];
    const float* bqkvu = (const float*)d_in[3];
    const float* Wout  = (const float*)d_in[4];
    const float* bout  = (const float*)d_in[5];
    const float* theta = (const float*)d_in[6];
    const float* ln_w  = (const float*)d_in[7];
    const float* ln_b  = (const float*)d_in[8];
    float* out = (float*)d_out;

    // workspace layout
    char* ws = (char*)d_ws;
    unsigned short* qkvu  = (unsigned short*)ws; ws += (size_t)ROWS * FOURD * 2;   // 32 MiB
    float*          kvbuf = (float*)ws;          ws += (size_t)B_ * H_ * 8192 * 4; // 1 MiB
    unsigned short* wqb   = (unsigned short*)ws; ws += (size_t)FOURD * D_ * 2;     // 8 MiB
    unsigned short* wob   = (unsigned short*)ws; ws += (size_t)D_ * D_ * 2;        // 2 MiB
    unsigned short* xb    = (unsigned short*)ws; ws += (size_t)ROWS * D_ * 2;      // 8 MiB
    unsigned short* cost  = (unsigned short*)ws; ws += (size_t)N_ * D_ * 2;        // 4 MiB
    unsigned short* sint  = (unsigned short*)ws; ws += (size_t)N_ * D_ * 2;        // 4 MiB
    float*          part  = (float*)ws;          // 16 MiB kv partials
    unsigned short* gb    = (unsigned short*)ws; // alias: part dead before attn writes g

    dim3 blk(256);
    // casts + lrpe table
    cast_table<<<dim3(2883584 / 256), blk, 0, stream>>>(
        x, Wqkvu, Wout, theta, xb, wqb, wob, cost, sint);

    // qkvu = x @ Wqkvu^T + b (bf16 out), silu on q,k columns
    gemm_bt_128<<<dim3(FOURD / 128, ROWS / 128), blk, 0, stream>>>(
        xb, wqb, bqkvu, qkvu, ROWS, FOURD, D_, 2 * D_);
    // KV partials (512 blocks) + reduce
    kv_mfma<<<dim3(32 * 16), blk, 0, stream>>>(qkvu, cost, sint, part);
    kv_reduce<<<dim3(32 * 8192 / 256), blk, 0, stream>>>(part, kvbuf);
    // o = lrpe(q) @ KV, fused LN + u gating -> g (bf16)
    attn_ln_kernel<<<dim3(ROWS / 8), blk, 0, stream>>>(
        qkvu, kvbuf, cost, sint, ln_w, ln_b, gb);
    // out = g @ Wout^T + bout
    gemm_bt_64<<<dim3(D_ / 64, ROWS / 128), blk, 0, stream>>>(
        gb, wob, bout, out, ROWS, D_, D_);
}

// Round 8
// 205.037 us; speedup vs baseline: 1.1491x; 1.0445x over previous
//
#include <hip/hip_runtime.h>
#include <math.h>

#define B_ 2
#define N_ 2048
#define D_ 1024
#define H_ 16
#define DH_ 64
#define ROWS (B_*N_)      // 4096
#define FOURD (4*D_)      // 4096
#define EPS_ 1e-5f

typedef short bf16x8 __attribute__((ext_vector_type(8)));
typedef unsigned short u16x8 __attribute__((ext_vector_type(8)));
typedef float f32x4  __attribute__((ext_vector_type(4)));

__device__ __forceinline__ unsigned short f2bf(float f) {
    unsigned int x = __float_as_uint(f);
    unsigned int r = (x + 0x7fffu + ((x >> 16) & 1u)) >> 16;   // RNE
    return (unsigned short)r;
}
__device__ __forceinline__ float bf2f(unsigned short u) {
    return __uint_as_float((unsigned int)u << 16);
}

// Barrier that does NOT drain vmcnt: waits lgkmcnt(0) only (LDS ordering),
// leaving prefetch buffer_loads in flight across the barrier. This is what
// __syncthreads() cannot express (it emits s_waitcnt vmcnt(0) first).
// s_waitcnt simm16: vmcnt[3:0]=0xF, expcnt[6:4]=7, lgkmcnt[11:8]=0, vmcnt[5:4]=b11
__device__ __forceinline__ void bar_lds() {
    __builtin_amdgcn_s_waitcnt(0xC07F);
    __builtin_amdgcn_s_barrier();
}

// ---------------------------------------------------------------------------
// fused: fp32->bf16 casts of x, Wqkvu, Wout + lrpe cos/sin bf16 tables
// ---------------------------------------------------------------------------
__global__ __launch_bounds__(256)
void cast_table(const float* __restrict__ x, const float* __restrict__ w1,
                const float* __restrict__ w2, const float* __restrict__ theta,
                unsigned short* __restrict__ xb, unsigned short* __restrict__ w1b,
                unsigned short* __restrict__ w2b, unsigned short* __restrict__ cos_t,
                unsigned short* __restrict__ sin_t)
{
    int i = blockIdx.x * 256 + threadIdx.x;
    if (i < 2359296) {
        const float* src; unsigned short* dst; int off;
        if (i < 1048576)      { src = x;  dst = xb;  off = i; }
        else if (i < 2097152) { src = w1; dst = w1b; off = i - 1048576; }
        else                  { src = w2; dst = w2b; off = i - 2097152; }
        float4 v = ((const float4*)src)[off];
        ushort4 o;
        o.x = f2bf(v.x); o.y = f2bf(v.y); o.z = f2bf(v.z); o.w = f2bf(v.w);
        ((ushort4*)dst)[off] = o;
    } else {
        int j  = i - 2359296;            // 0..524287
        int n  = j >> 8;                 // 0..2047
        int c0 = (j & 255) * 4;
        float4 tv = *(const float4*)&theta[c0];
        float t[4] = {tv.x, tv.y, tv.z, tv.w};
        ushort4 co, si;
        unsigned short* cp = (unsigned short*)&co;
        unsigned short* sp = (unsigned short*)&si;
#pragma unroll
        for (int k = 0; k < 4; ++k) {
            float s, c; __sincosf(t[k] * (float)n, &s, &c);
            cp[k] = f2bf(c); sp[k] = f2bf(s);
        }
        *(ushort4*)&cos_t[(size_t)n * D_ + c0] = co;
        *(ushort4*)&sin_t[(size_t)n * D_ + c0] = si;
    }
}

// ---------------------------------------------------------------------------
// bf16 MFMA GEMM, 128x128 tile, BK=64, XOR-swizzled LDS (0 conflicts, r5/r7),
// 16x16x32 MFMA. PIPELINED: register prefetch of tile t+1 overlaps MFMA of
// tile t; raw lgkm-only barriers keep the prefetch loads in flight.
// NOTE: do NOT switch to 32x32 MFMA with this layout (4-way conflicts, r6).
// ---------------------------------------------------------------------------
__global__ __launch_bounds__(256, 2)
void gemm_bt_128(const unsigned short* __restrict__ A,
                 const unsigned short* __restrict__ Bw,
                 const float* __restrict__ bias, unsigned short* __restrict__ C,
                 int M, int N, int K, int siluLim)
{
    __shared__ unsigned short As[128 * 64];
    __shared__ unsigned short Bs[128 * 64];

    const int tid  = threadIdx.x;
    const int row0 = blockIdx.y * 128;
    const int col0 = blockIdx.x * 128;
    const int wave = tid >> 6;
    const int lane = tid & 63;
    const int wr   = (wave >> 1) * 64;
    const int wc   = (wave & 1) * 64;
    const int l15  = lane & 15;
    const int quad = lane >> 4;
    const int xr   = l15 & 7;            // read-side xor key (row&7 == l15&7)

    f32x4 acc[4][4] = {};

    // staging map: thread -> (row = tid>>3 (+32s), slot = tid&7);
    // global chunk = slot ^ (row&7); LDS dest = lane-linear 16B (conflict-free)
    const int srow = tid >> 3;
    const int skk  = ((tid & 7) ^ (srow & 7)) * 8;
    const unsigned short* ag = A  + (size_t)(row0 + srow) * K + skk;
    const unsigned short* bg = Bw + (size_t)(col0 + srow) * K + skk;

    // prologue: prefetch tile 0 into registers
    u16x8 apre[4], bpre[4];
#pragma unroll
    for (int s = 0; s < 4; ++s) {
        apre[s] = *(const u16x8*)(ag + (size_t)(32 * s) * K);
        bpre[s] = *(const u16x8*)(bg + (size_t)(32 * s) * K);
    }

    for (int k0 = 0; k0 < K; k0 += 64) {
        // commit prefetched tile to LDS (vmcnt wait lands here, after the
        // previous iteration's full MFMA phase)
#pragma unroll
        for (int s = 0; s < 4; ++s) {
            *(u16x8*)&As[tid * 8 + s * 2048] = apre[s];
            *(u16x8*)&Bs[tid * 8 + s * 2048] = bpre[s];
        }
        bar_lds();

        // issue prefetch for tile t+1 (stays in flight across compute+barrier)
        if (k0 + 64 < K) {
#pragma unroll
            for (int s = 0; s < 4; ++s) {
                apre[s] = *(const u16x8*)(ag + (size_t)(32 * s) * K + k0 + 64);
                bpre[s] = *(const u16x8*)(bg + (size_t)(32 * s) * K + k0 + 64);
            }
        }

#pragma unroll
        for (int ksub = 0; ksub < 2; ++ksub) {
            const int slot = ((ksub * 4 + quad) ^ xr) * 8;
            bf16x8 af[4], bfr[4];
#pragma unroll
            for (int i = 0; i < 4; ++i)
                af[i] = *(const bf16x8*)&As[(wr + i * 16 + l15) * 64 + slot];
#pragma unroll
            for (int j = 0; j < 4; ++j)
                bfr[j] = *(const bf16x8*)&Bs[(wc + j * 16 + l15) * 64 + slot];
#pragma unroll
            for (int i = 0; i < 4; ++i)
#pragma unroll
                for (int j = 0; j < 4; ++j)
                    acc[i][j] = __builtin_amdgcn_mfma_f32_16x16x32_bf16(af[i], bfr[j], acc[i][j], 0, 0, 0);
        }
        bar_lds();
    }

#pragma unroll
    for (int i = 0; i < 4; ++i) {
        const int r0 = row0 + wr + i * 16 + quad * 4;
#pragma unroll
        for (int j = 0; j < 4; ++j) {
            const int c = col0 + wc + j * 16 + l15;
            const float bb = bias[c];
#pragma unroll
            for (int r = 0; r < 4; ++r) {
                float v = acc[i][j][r] + bb;
                if (c < siluLim) v = v / (1.f + __expf(-v));   // silu (HW exp)
                C[(size_t)(r0 + r) * N + c] = f2bf(v);
            }
        }
    }
}

// ---------------------------------------------------------------------------
// bf16 MFMA GEMM, 128x64 tile, BK=64, same swizzle + same pipeline; fp32 out.
// ---------------------------------------------------------------------------
__global__ __launch_bounds__(256, 2)
void gemm_bt_64(const unsigned short* __restrict__ A,
                const unsigned short* __restrict__ Bw,
                const float* __restrict__ bias, float* __restrict__ C,
                int M, int N, int K)
{
    __shared__ unsigned short As[128 * 64];
    __shared__ unsigned short Bs[64 * 64];

    const int tid  = threadIdx.x;
    const int row0 = blockIdx.y * 128;
    const int col0 = blockIdx.x * 64;
    const int wave = tid >> 6;
    const int lane = tid & 63;
    const int wr   = wave * 32;
    const int l15  = lane & 15;
    const int quad = lane >> 4;
    const int xr   = l15 & 7;

    f32x4 acc[2][4] = {};

    const int srow = tid >> 3;
    const int skk  = ((tid & 7) ^ (srow & 7)) * 8;
    const unsigned short* ag = A  + (size_t)(row0 + srow) * K + skk;
    const unsigned short* bg = Bw + (size_t)(col0 + srow) * K + skk;

    u16x8 apre[4], bpre[2];
#pragma unroll
    for (int s = 0; s < 4; ++s)
        apre[s] = *(const u16x8*)(ag + (size_t)(32 * s) * K);
#pragma unroll
    for (int s = 0; s < 2; ++s)
        bpre[s] = *(const u16x8*)(bg + (size_t)(32 * s) * K);

    for (int k0 = 0; k0 < K; k0 += 64) {
#pragma unroll
        for (int s = 0; s < 4; ++s)
            *(u16x8*)&As[tid * 8 + s * 2048] = apre[s];
#pragma unroll
        for (int s = 0; s < 2; ++s)
            *(u16x8*)&Bs[tid * 8 + s * 2048] = bpre[s];
        bar_lds();

        if (k0 + 64 < K) {
#pragma unroll
            for (int s = 0; s < 4; ++s)
                apre[s] = *(const u16x8*)(ag + (size_t)(32 * s) * K + k0 + 64);
#pragma unroll
            for (int s = 0; s < 2; ++s)
                bpre[s] = *(const u16x8*)(bg + (size_t)(32 * s) * K + k0 + 64);
        }

#pragma unroll
        for (int ksub = 0; ksub < 2; ++ksub) {
            const int slot = ((ksub * 4 + quad) ^ xr) * 8;
            bf16x8 af[2], bfr[4];
#pragma unroll
            for (int i = 0; i < 2; ++i)
                af[i] = *(const bf16x8*)&As[(wr + i * 16 + l15) * 64 + slot];
#pragma unroll
            for (int j = 0; j < 4; ++j)
                bfr[j] = *(const bf16x8*)&Bs[(j * 16 + l15) * 64 + slot];
#pragma unroll
            for (int i = 0; i < 2; ++i)
#pragma unroll
                for (int j = 0; j < 4; ++j)
                    acc[i][j] = __builtin_amdgcn_mfma_f32_16x16x32_bf16(af[i], bfr[j], acc[i][j], 0, 0, 0);
        }
        bar_lds();
    }

#pragma unroll
    for (int i = 0; i < 2; ++i) {
        const int r0 = row0 + wr + i * 16 + quad * 4;
#pragma unroll
        for (int j = 0; j < 4; ++j) {
            const int c = col0 + j * 16 + l15;
            const float bb = bias[c];
#pragma unroll
            for (int r = 0; r < 4; ++r)
                C[(size_t)(r0 + r) * N + c] = acc[i][j][r] + bb;
        }
    }
}

// ---------------------------------------------------------------------------
// kv_mfma: per (b,h, 128-n chunk): partial KV[128 d, 64 e] via MFMA.
// grid = 512 blocks. Table-based lrpe staging, fp32 partials (no atomics).
// ---------------------------------------------------------------------------
__global__ __launch_bounds__(256)
void kv_mfma(const unsigned short* __restrict__ qkvu,
             const unsigned short* __restrict__ cos_t,
             const unsigned short* __restrict__ sin_t,
             float* __restrict__ part)
{
    __shared__ unsigned short kl_s[128][136];  // [d][n], 128 + 8 pad
    __shared__ unsigned short v_s [64][136];   // [e][n]

    const int bid   = blockIdx.x;
    const int chunk = bid & 15;
    const int bh    = bid >> 4;
    const int h     = bh & 15;
    const int b     = bh >> 4;
    const int tid   = threadIdx.x;
    const int lane  = tid & 63;
    const int wave  = tid >> 6;
    const int l15   = lane & 15;
    const int quad  = lane >> 4;
    const int n0    = chunk * 128;

    {
        const int g   = tid & 7;
        const int nn0 = (tid >> 3) * 4;
        ushort4 pc[8], ps[8], pv[8];
#pragma unroll
        for (int r = 0; r < 4; ++r) {
            const int n = n0 + nn0 + r;
            const unsigned short* qrow = qkvu + (size_t)(b * N_ + n) * FOURD;
            u16x8 k8 = *(const u16x8*)(qrow + D_     + h * DH_ + g * 8);
            u16x8 v8 = *(const u16x8*)(qrow + 2 * D_ + h * DH_ + g * 8);
            u16x8 c8 = *(const u16x8*)(cos_t + (size_t)n * D_ + h * DH_ + g * 8);
            u16x8 s8 = *(const u16x8*)(sin_t + (size_t)n * D_ + h * DH_ + g * 8);
#pragma unroll
            for (int j = 0; j < 8; ++j) {
                const float kf = bf2f(k8[j]);
                ((unsigned short*)&pc[j])[r] = f2bf(kf * bf2f(c8[j]));
                ((unsigned short*)&ps[j])[r] = f2bf(kf * bf2f(s8[j]));
                ((unsigned short*)&pv[j])[r] = v8[j];
            }
        }
#pragma unroll
        for (int j = 0; j < 8; ++j) {
            const int dh = g * 8 + j;
            *(ushort4*)&kl_s[dh][nn0]      = pc[j];
            *(ushort4*)&kl_s[64 + dh][nn0] = ps[j];
            *(ushort4*)&v_s[dh][nn0]       = pv[j];
        }
    }
    __syncthreads();

    f32x4 acc[2][4] = {};
#pragma unroll
    for (int ks = 0; ks < 4; ++ks) {            // 128 n in steps of 32
        bf16x8 a0 = *(const bf16x8*)&kl_s[wave * 32 +      l15][ks * 32 + quad * 8];
        bf16x8 a1 = *(const bf16x8*)&kl_s[wave * 32 + 16 + l15][ks * 32 + quad * 8];
#pragma unroll
        for (int j = 0; j < 4; ++j) {
            bf16x8 bfr = *(const bf16x8*)&v_s[j * 16 + l15][ks * 32 + quad * 8];
            acc[0][j] = __builtin_amdgcn_mfma_f32_16x16x32_bf16(a0, bfr, acc[0][j], 0, 0, 0);
            acc[1][j] = __builtin_amdgcn_mfma_f32_16x16x32_bf16(a1, bfr, acc[1][j], 0, 0, 0);
        }
    }

    float* pp = part + ((size_t)bh * 16 + chunk) * 8192;
#pragma unroll
    for (int i = 0; i < 2; ++i) {
        const int d0 = wave * 32 + i * 16 + quad * 4;
#pragma unroll
        for (int j = 0; j < 4; ++j) {
            const int e = j * 16 + l15;
#pragma unroll
            for (int r = 0; r < 4; ++r)
                pp[(d0 + r) * 64 + e] = acc[i][j][r];
        }
    }
}

// ---------------------------------------------------------------------------
// kv_reduce: kv[bh][i] = sum over 16 chunk partials.
// ---------------------------------------------------------------------------
__global__ __launch_bounds__(256)
void kv_reduce(const float* __restrict__ part, float* __restrict__ kv)
{
    const int i  = blockIdx.x * 256 + threadIdx.x;
    const int bh = i >> 13;
    const float* pp = part + ((size_t)bh * 16) * 8192 + (i & 8191);
    float s = 0.f;
#pragma unroll
    for (int c = 0; c < 16; ++c) s += pp[c * 8192];
    kv[i] = s;
}

// ---------------------------------------------------------------------------
// attn_ln: 8 rows per block. o = lrpe(q) @ KV (fp32), fused LayerNorm +
// u gating, bf16 output. Table-based lrpe.
// ---------------------------------------------------------------------------
__global__ __launch_bounds__(256)
void attn_ln_kernel(const unsigned short* __restrict__ qkvu, const float* __restrict__ kvb,
                    const unsigned short* __restrict__ cos_t,
                    const unsigned short* __restrict__ sin_t,
                    const float* __restrict__ ln_w, const float* __restrict__ ln_b,
                    unsigned short* __restrict__ g)
{
    __shared__ float qc_s[8][1024];
    __shared__ float qs_s[8][1024];
    __shared__ float red[4][16];
    __shared__ float mured[8], rsred[8];

    const int row0 = blockIdx.x * 8;
    const int b    = row0 >> 11;
    const int tid  = threadIdx.x;
    const int lane = tid & 63;
    const int wave = tid >> 6;

    for (int i = tid; i < 2048; i += 256) {
        const int r  = i >> 8;
        const int ci = (i & 255) * 4;
        const int n  = (row0 + r) & (N_ - 1);
        ushort4 qv = *(const ushort4*)&qkvu[(size_t)(row0 + r) * FOURD + ci];
        ushort4 cv = *(const ushort4*)&cos_t[(size_t)n * D_ + ci];
        ushort4 sv = *(const ushort4*)&sin_t[(size_t)n * D_ + ci];
        float4 co, so;
        co.x = bf2f(qv.x) * bf2f(cv.x); so.x = bf2f(qv.x) * bf2f(sv.x);
        co.y = bf2f(qv.y) * bf2f(cv.y); so.y = bf2f(qv.y) * bf2f(sv.y);
        co.z = bf2f(qv.z) * bf2f(cv.z); so.z = bf2f(qv.z) * bf2f(sv.z);
        co.w = bf2f(qv.w) * bf2f(cv.w); so.w = bf2f(qv.w) * bf2f(sv.w);
        *(float4*)&qc_s[r][ci] = co;
        *(float4*)&qs_s[r][ci] = so;
    }
    __syncthreads();

    const int c0 = tid * 4;
    const int h  = c0 >> 6;
    const int e0 = c0 & 63;
    const float* kvp = kvb + (size_t)(b * H_ + h) * 8192;

    float o[8][4] = {};
    for (int d = 0; d < 64; ++d) {
        float4 kc = *(const float4*)&kvp[d * 64 + e0];
        float4 ks = *(const float4*)&kvp[(64 + d) * 64 + e0];
#pragma unroll
        for (int r = 0; r < 8; ++r) {
            const float qc = qc_s[r][h * 64 + d];
            const float qs = qs_s[r][h * 64 + d];
            o[r][0] = fmaf(qc, kc.x, fmaf(qs, ks.x, o[r][0]));
            o[r][1] = fmaf(qc, kc.y, fmaf(qs, ks.y, o[r][1]));
            o[r][2] = fmaf(qc, kc.z, fmaf(qs, ks.z, o[r][2]));
            o[r][3] = fmaf(qc, kc.w, fmaf(qs, ks.w, o[r][3]));
        }
    }

    float sum[8], sq[8];
#pragma unroll
    for (int r = 0; r < 8; ++r) {
        sum[r] = o[r][0] + o[r][1] + o[r][2] + o[r][3];
        sq[r]  = o[r][0]*o[r][0] + o[r][1]*o[r][1] + o[r][2]*o[r][2] + o[r][3]*o[r][3];
    }
#pragma unroll
    for (int off = 32; off; off >>= 1)
#pragma unroll
        for (int r = 0; r < 8; ++r) {
            sum[r] += __shfl_down(sum[r], off, 64);
            sq[r]  += __shfl_down(sq[r],  off, 64);
        }
    if (lane == 0)
#pragma unroll
        for (int r = 0; r < 8; ++r) { red[wave][r] = sum[r]; red[wave][8 + r] = sq[r]; }
    __syncthreads();
    if (tid < 8) {
        const float s  = red[0][tid] + red[1][tid] + red[2][tid] + red[3][tid];
        const float q2 = red[0][8+tid] + red[1][8+tid] + red[2][8+tid] + red[3][8+tid];
        const float mu = s * (1.f / (float)D_);
        const float var = q2 * (1.f / (float)D_) - mu * mu;
        mured[tid] = mu;
        rsred[tid] = rsqrtf(var + EPS_);
    }
    __syncthreads();

    float4 wv = *(const float4*)&ln_w[c0];
    float4 bv = *(const float4*)&ln_b[c0];
#pragma unroll
    for (int r = 0; r < 8; ++r) {
        ushort4 uvb = *(const ushort4*)&qkvu[(size_t)(row0 + r) * FOURD + 3 * D_ + c0];
        const float mu = mured[r], rs = rsred[r];
        ushort4 ov;
        ov.x = f2bf(((o[r][0] - mu) * rs * wv.x + bv.x) * bf2f(uvb.x));
        ov.y = f2bf(((o[r][1] - mu) * rs * wv.y + bv.y) * bf2f(uvb.y));
        ov.z = f2bf(((o[r][2] - mu) * rs * wv.z + bv.z) * bf2f(uvb.z));
        ov.w = f2bf(((o[r][3] - mu) * rs * wv.w + bv.w) * bf2f(uvb.w));
        *(ushort4*)&g[(size_t)(row0 + r) * D_ + c0] = ov;
    }
}

// ---------------------------------------------------------------------------
extern "C" void kernel_launch(void* const* d_in, const int* in_sizes, int n_in,
                              void* d_out, int out_size, void* d_ws, size_t ws_size,
                              hipStream_t stream)
{
    const float* x     = (const float*)d_in[0];
    const float* Wqkvu = (const float*)d_in[2];
    const float* bqkvu = (const float*)d_in[3];
    const float* Wout  = (const float*)d_in[4];
    const float* bout  = (const float*)d_in[5];
    const float* theta = (const float*)d_in[6];
    const float* ln_w  = (const float*)d_in[7];
    const float* ln_b  = (const float*)d_in[8];
    float* out = (float*)d_out;

    // workspace layout
    char* ws = (char*)d_ws;
    unsigned short* qkvu  = (unsigned short*)ws; ws += (size_t)ROWS * FOURD * 2;   // 32 MiB
    float*          kvbuf = (float*)ws;          ws += (size_t)B_ * H_ * 8192 * 4; // 1 MiB
    unsigned short* wqb   = (unsigned short*)ws; ws += (size_t)FOURD * D_ * 2;     // 8 MiB
    unsigned short* wob   = (unsigned short*)ws; ws += (size_t)D_ * D_ * 2;        // 2 MiB
    unsigned short* xb    = (unsigned short*)ws; ws += (size_t)ROWS * D_ * 2;      // 8 MiB
    unsigned short* cost  = (unsigned short*)ws; ws += (size_t)N_ * D_ * 2;        // 4 MiB
    unsigned short* sint  = (unsigned short*)ws; ws += (size_t)N_ * D_ * 2;        // 4 MiB
    float*          part  = (float*)ws;          // 16 MiB kv partials
    unsigned short* gb    = (unsigned short*)ws; // alias: part dead before attn writes g

    dim3 blk(256);
    // casts + lrpe table
    cast_table<<<dim3(2883584 / 256), blk, 0, stream>>>(
        x, Wqkvu, Wout, theta, xb, wqb, wob, cost, sint);

    // qkvu = x @ Wqkvu^T + b (bf16 out), silu on q,k columns
    gemm_bt_128<<<dim3(FOURD / 128, ROWS / 128), blk, 0, stream>>>(
        xb, wqb, bqkvu, qkvu, ROWS, FOURD, D_, 2 * D_);
    // KV partials (512 blocks) + reduce
    kv_mfma<<<dim3(32 * 16), blk, 0, stream>>>(qkvu, cost, sint, part);
    kv_reduce<<<dim3(32 * 8192 / 256), blk, 0, stream>>>(part, kvbuf);
    // o = lrpe(q) @ KV, fused LN + u gating -> g (bf16)
    attn_ln_kernel<<<dim3(ROWS / 8), blk, 0, stream>>>(
        qkvu, kvbuf, cost, sint, ln_w, ln_b, gb);
    // out = g @ Wout^T + bout
    gemm_bt_64<<<dim3(D_ / 64, ROWS / 128), blk, 0, stream>>>(
        gb, wob, bout, out, ROWS, D_, D_);
}